// Round 1
// baseline (8378.935 us; speedup 1.0000x reference)
//
#include <hip/hip_runtime.h>
#include <hip/hip_bf16.h>

#define N_NODES 150000
#define M_HYPER 50000
#define N_TOTAL 200000
#define DIM 64
#define NCLASS 50
#define NNZ 3200000

// ---------------------------------------------------------------------------
// SpMM: y[rows[e], :] += vals[e] * x[cols[e], :]
// 16 threads per nnz, each thread handles a float4 (16B) of the 64-dim row.
// ---------------------------------------------------------------------------
__global__ __launch_bounds__(256) void spmm_atomic(
    const float* __restrict__ vals, const int* __restrict__ rows,
    const int* __restrict__ cols, const float* __restrict__ x,
    float* __restrict__ y) {
    long long gid = (long long)blockIdx.x * blockDim.x + threadIdx.x;
    int e = (int)(gid >> 4);
    int lane = (int)(gid & 15);
    if (e >= NNZ) return;
    int r = rows[e];
    int c = cols[e];
    float v = vals[e];
    const float4 xv = *reinterpret_cast<const float4*>(x + (size_t)c * DIM + lane * 4);
    float* yp = y + (size_t)r * DIM + lane * 4;
    atomicAdd(yp + 0, xv.x * v);
    atomicAdd(yp + 1, xv.y * v);
    atomicAdd(yp + 2, xv.z * v);
    atomicAdd(yp + 3, xv.w * v);
}

// ---------------------------------------------------------------------------
// Partial GEMM accumulate: Z[row, :] += X[row, 0:64] @ W (64x50), rows < nrows
// One thread per row; W staged in LDS; x row in 64 VGPRs.
// ---------------------------------------------------------------------------
__global__ __launch_bounds__(256) void gemm_acc(
    const float* __restrict__ X, const float* __restrict__ W,
    float* __restrict__ Z, int nrows) {
    __shared__ float Ws[DIM * NCLASS];
    for (int i = threadIdx.x; i < DIM * NCLASS; i += 256) Ws[i] = W[i];
    __syncthreads();
    int row = blockIdx.x * blockDim.x + threadIdx.x;
    if (row >= nrows) return;
    float xr[DIM];
    const float4* xp = reinterpret_cast<const float4*>(X + (size_t)row * DIM);
#pragma unroll
    for (int i = 0; i < DIM / 4; ++i) reinterpret_cast<float4*>(xr)[i] = xp[i];
    float* zp = Z + (size_t)row * NCLASS;
    for (int c = 0; c < NCLASS; ++c) {
        float acc = 0.f;
#pragma unroll
        for (int k = 0; k < DIM; ++k) acc += xr[k] * Ws[k * NCLASS + c];
        zp[c] += acc;
    }
}

// ---------------------------------------------------------------------------
// Finalize: Z = log_softmax(Z/4 + b)
// ---------------------------------------------------------------------------
__global__ __launch_bounds__(256) void finalize_kernel(
    float* __restrict__ Z, const float* __restrict__ b) {
    __shared__ float bs[NCLASS];
    if (threadIdx.x < NCLASS) bs[threadIdx.x] = b[threadIdx.x];
    __syncthreads();
    int row = blockIdx.x * blockDim.x + threadIdx.x;
    if (row >= N_NODES) return;
    float* zp = Z + (size_t)row * NCLASS;
    float z[NCLASS];
    float m = -1e30f;
#pragma unroll
    for (int c = 0; c < NCLASS; ++c) {
        z[c] = zp[c] * 0.25f + bs[c];
        m = fmaxf(m, z[c]);
    }
    float s = 0.f;
#pragma unroll
    for (int c = 0; c < NCLASS; ++c) s += __expf(z[c] - m);
    float ls = m + __logf(s);
#pragma unroll
    for (int c = 0; c < NCLASS; ++c) zp[c] = z[c] - ls;
}

extern "C" void kernel_launch(void* const* d_in, const int* in_sizes, int n_in,
                              void* d_out, int out_size, void* d_ws, size_t ws_size,
                              hipStream_t stream) {
    const float* node_emb = (const float*)d_in[0];
    const float* hyper_emb = (const float*)d_in[1];
    const float* W = (const float*)d_in[2];
    const float* b = (const float*)d_in[3];
    const float* vals = (const float*)d_in[4];
    const int* rows = (const int*)d_in[5];
    const int* cols = (const int*)d_in[6];
    float* Z = (float*)d_out;

    float* x = (float*)d_ws;
    float* y = x + (size_t)N_TOTAL * DIM;

    // Build all_emb in x
    hipMemcpyAsync(x, node_emb, (size_t)N_NODES * DIM * sizeof(float),
                   hipMemcpyDeviceToDevice, stream);
    hipMemcpyAsync(x + (size_t)N_NODES * DIM, hyper_emb,
                   (size_t)M_HYPER * DIM * sizeof(float),
                   hipMemcpyDeviceToDevice, stream);
    // Zero Z accumulator
    hipMemsetAsync(Z, 0, (size_t)out_size * sizeof(float), stream);

    const int gemm_blocks = (N_NODES + 255) / 256;
    // Layer-0 contribution (all_emb itself)
    gemm_acc<<<gemm_blocks, 256, 0, stream>>>(x, W, Z, N_NODES);

    const long long spmm_threads = (long long)NNZ * 16;
    const int spmm_blocks = (int)((spmm_threads + 255) / 256);

    for (int l = 0; l < 3; ++l) {
        hipMemsetAsync(y, 0, (size_t)N_TOTAL * DIM * sizeof(float), stream);
        spmm_atomic<<<spmm_blocks, 256, 0, stream>>>(vals, rows, cols, x, y);
        gemm_acc<<<gemm_blocks, 256, 0, stream>>>(y, W, Z, N_NODES);
        float* t = x; x = y; y = t;
    }
    finalize_kernel<<<gemm_blocks, 256, 0, stream>>>(Z, b);
}

// Round 2
// 1660.388 us; speedup vs baseline: 5.0464x; 5.0464x over previous
//
#include <hip/hip_runtime.h>
#include <hip/hip_bf16.h>

#define N_NODES 150000
#define M_HYPER 50000
#define N_TOTAL 200000
#define DIM 64
#define NCLASS 50
#define NNZ 3200000

// ---------------------------------------------------------------------------
// CSR build step 1: histogram of rows
// ---------------------------------------------------------------------------
__global__ __launch_bounds__(256) void hist_rows(const int* __restrict__ rows,
                                                 int* __restrict__ cnt) {
    int e = blockIdx.x * 256 + threadIdx.x;
    if (e < NNZ) atomicAdd(&cnt[rows[e]], 1);
}

// ---------------------------------------------------------------------------
// CSR build step 2: single-block chunked exclusive scan over 200k counts.
// Each thread owns a contiguous chunk; block-level Hillis-Steele over partials.
// Writes row_ptr (exclusive offsets) and cursor (scatter cursors).
// ---------------------------------------------------------------------------
__global__ __launch_bounds__(1024) void scan_counts(const int* __restrict__ cnt,
                                                    int* __restrict__ row_ptr,
                                                    int* __restrict__ cursor) {
    __shared__ int part[1024];
    const int CH = (N_TOTAL + 1023) / 1024;  // 196
    int t = threadIdx.x;
    int beg = t * CH;
    int end = beg + CH; if (end > N_TOTAL) end = N_TOTAL;
    int s = 0;
    for (int i = beg; i < end; ++i) s += cnt[i];
    part[t] = s;
    __syncthreads();
    for (int off = 1; off < 1024; off <<= 1) {
        int add = (t >= off) ? part[t - off] : 0;
        __syncthreads();
        part[t] += add;
        __syncthreads();
    }
    int run = (t == 0) ? 0 : part[t - 1];
    for (int i = beg; i < end; ++i) {
        int c = cnt[i];
        row_ptr[i] = run;
        cursor[i] = run;
        run += c;
    }
    if (t == 1023) row_ptr[N_TOTAL] = run;  // == NNZ
}

// ---------------------------------------------------------------------------
// CSR build step 3: scatter (col, val) into row-sorted order
// ---------------------------------------------------------------------------
__global__ __launch_bounds__(256) void scatter_edges(
    const int* __restrict__ rows, const int* __restrict__ cols,
    const float* __restrict__ vals, int* __restrict__ cursor,
    int* __restrict__ scol, float* __restrict__ sval) {
    int e = blockIdx.x * 256 + threadIdx.x;
    if (e >= NNZ) return;
    int r = rows[e];
    int p = atomicAdd(&cursor[r], 1);
    scol[p] = cols[e];
    sval[p] = vals[e];
}

// ---------------------------------------------------------------------------
// SpMM gather: one wave per output row, lane = dim element.
// y[r, lane] = sum over row r's edges of val * x[col, lane]
// ---------------------------------------------------------------------------
__global__ __launch_bounds__(256) void spmm_gather(
    const int* __restrict__ row_ptr, const int* __restrict__ scol,
    const float* __restrict__ sval, const float* __restrict__ x,
    float* __restrict__ y) {
    int wid = (blockIdx.x * 256 + threadIdx.x) >> 6;
    int lane = threadIdx.x & 63;
    if (wid >= N_TOTAL) return;
    int beg = row_ptr[wid], end = row_ptr[wid + 1];
    float acc = 0.f;
    int k = beg;
    for (; k + 1 < end; k += 2) {
        int c0 = scol[k], c1 = scol[k + 1];
        float v0 = sval[k], v1 = sval[k + 1];
        acc += v0 * x[(size_t)c0 * DIM + lane];
        acc += v1 * x[(size_t)c1 * DIM + lane];
    }
    if (k < end) acc += sval[k] * x[(size_t)scol[k] * DIM + lane];
    y[(size_t)wid * DIM + lane] = acc;
}

// ---------------------------------------------------------------------------
// Partial GEMM accumulate: Z[row, :] += X[row, 0:64] @ W (64x50)
// ---------------------------------------------------------------------------
__global__ __launch_bounds__(256) void gemm_acc(
    const float* __restrict__ X, const float* __restrict__ W,
    float* __restrict__ Z, int nrows) {
    __shared__ float Ws[DIM * NCLASS];
    for (int i = threadIdx.x; i < DIM * NCLASS; i += 256) Ws[i] = W[i];
    __syncthreads();
    int row = blockIdx.x * blockDim.x + threadIdx.x;
    if (row >= nrows) return;
    float xr[DIM];
    const float4* xp = reinterpret_cast<const float4*>(X + (size_t)row * DIM);
#pragma unroll
    for (int i = 0; i < DIM / 4; ++i) reinterpret_cast<float4*>(xr)[i] = xp[i];
    float* zp = Z + (size_t)row * NCLASS;
    for (int c = 0; c < NCLASS; ++c) {
        float acc = 0.f;
#pragma unroll
        for (int k = 0; k < DIM; ++k) acc += xr[k] * Ws[k * NCLASS + c];
        zp[c] += acc;
    }
}

// ---------------------------------------------------------------------------
// Finalize: Z = log_softmax(Z/4 + b)
// ---------------------------------------------------------------------------
__global__ __launch_bounds__(256) void finalize_kernel(
    float* __restrict__ Z, const float* __restrict__ b) {
    __shared__ float bs[NCLASS];
    if (threadIdx.x < NCLASS) bs[threadIdx.x] = b[threadIdx.x];
    __syncthreads();
    int row = blockIdx.x * blockDim.x + threadIdx.x;
    if (row >= N_NODES) return;
    float* zp = Z + (size_t)row * NCLASS;
    float z[NCLASS];
    float m = -1e30f;
#pragma unroll
    for (int c = 0; c < NCLASS; ++c) {
        z[c] = zp[c] * 0.25f + bs[c];
        m = fmaxf(m, z[c]);
    }
    float s = 0.f;
#pragma unroll
    for (int c = 0; c < NCLASS; ++c) s += __expf(z[c] - m);
    float ls = m + __logf(s);
#pragma unroll
    for (int c = 0; c < NCLASS; ++c) zp[c] = z[c] - ls;
}

extern "C" void kernel_launch(void* const* d_in, const int* in_sizes, int n_in,
                              void* d_out, int out_size, void* d_ws, size_t ws_size,
                              hipStream_t stream) {
    const float* node_emb = (const float*)d_in[0];
    const float* hyper_emb = (const float*)d_in[1];
    const float* W = (const float*)d_in[2];
    const float* b = (const float*)d_in[3];
    const float* vals = (const float*)d_in[4];
    const int* rows = (const int*)d_in[5];
    const int* cols = (const int*)d_in[6];
    float* Z = (float*)d_out;

    // Workspace layout (bytes): x(51.2M) y(51.2M) sval(12.8M) scol(12.8M)
    //                           cnt(0.8M) row_ptr(0.8M) cursor(0.8M)
    char* w = (char*)d_ws;
    float* x = (float*)w;                 w += (size_t)N_TOTAL * DIM * 4;
    float* y = (float*)w;                 w += (size_t)N_TOTAL * DIM * 4;
    float* sval = (float*)w;              w += (size_t)NNZ * 4;
    int* scol = (int*)w;                  w += (size_t)NNZ * 4;
    int* cnt = (int*)w;                   w += (size_t)N_TOTAL * 4;
    int* row_ptr = (int*)w;               w += (size_t)(N_TOTAL + 1) * 4;
    int* cursor = (int*)w;

    // ---- CSR build ----
    hipMemsetAsync(cnt, 0, (size_t)N_TOTAL * 4, stream);
    hist_rows<<<(NNZ + 255) / 256, 256, 0, stream>>>(rows, cnt);
    scan_counts<<<1, 1024, 0, stream>>>(cnt, row_ptr, cursor);
    scatter_edges<<<(NNZ + 255) / 256, 256, 0, stream>>>(rows, cols, vals,
                                                         cursor, scol, sval);

    // ---- Build all_emb in x ----
    hipMemcpyAsync(x, node_emb, (size_t)N_NODES * DIM * 4,
                   hipMemcpyDeviceToDevice, stream);
    hipMemcpyAsync(x + (size_t)N_NODES * DIM, hyper_emb,
                   (size_t)M_HYPER * DIM * 4, hipMemcpyDeviceToDevice, stream);
    hipMemsetAsync(Z, 0, (size_t)out_size * 4, stream);

    const int gemm_blocks = (N_NODES + 255) / 256;
    gemm_acc<<<gemm_blocks, 256, 0, stream>>>(x, W, Z, N_NODES);

    const int spmm_blocks = (N_TOTAL * 64 + 255) / 256;  // one wave per row
    for (int l = 0; l < 3; ++l) {
        spmm_gather<<<spmm_blocks, 256, 0, stream>>>(row_ptr, scol, sval, x, y);
        gemm_acc<<<gemm_blocks, 256, 0, stream>>>(y, W, Z, N_NODES);
        float* t = x; x = y; y = t;
    }
    finalize_kernel<<<gemm_blocks, 256, 0, stream>>>(Z, b);
}

// Round 3
// 989.677 us; speedup vs baseline: 8.4663x; 1.6777x over previous
//
#include <hip/hip_runtime.h>
#include <hip/hip_bf16.h>

#define N_NODES 150000
#define M_HYPER 50000
#define N_TOTAL 200000
#define DIM 64
#define NCLASS 50
#define NNZ 3200000

#define SCAN_CHUNK 1024
#define NBLK1 ((N_TOTAL + SCAN_CHUNK - 1) / SCAN_CHUNK)  // 196

// ---------------------------------------------------------------------------
// CSR build step 1: histogram of rows
// ---------------------------------------------------------------------------
__global__ __launch_bounds__(256) void hist_rows(const int* __restrict__ rows,
                                                 int* __restrict__ cnt) {
    int e = blockIdx.x * 256 + threadIdx.x;
    if (e < NNZ) atomicAdd(&cnt[rows[e]], 1);
}

// ---------------------------------------------------------------------------
// Parallel exclusive scan over cnt[N_TOTAL], 3 phases.
// ---------------------------------------------------------------------------
__global__ __launch_bounds__(256) void scan_phase1(const int* __restrict__ cnt,
                                                   int* __restrict__ blk_sum) {
    __shared__ int sh[256];
    int b = blockIdx.x, t = threadIdx.x;
    int base = b * SCAN_CHUNK + t * 4;
    int s = 0;
#pragma unroll
    for (int i = 0; i < 4; ++i) {
        int idx = base + i;
        if (idx < N_TOTAL) s += cnt[idx];
    }
    sh[t] = s;
    __syncthreads();
    for (int off = 128; off > 0; off >>= 1) {
        if (t < off) sh[t] += sh[t + off];
        __syncthreads();
    }
    if (t == 0) blk_sum[b] = sh[0];
}

__global__ __launch_bounds__(256) void scan_phase2(const int* __restrict__ blk_sum,
                                                   int* __restrict__ blk_off,
                                                   int* __restrict__ row_ptr) {
    __shared__ int sh[256];
    int t = threadIdx.x;
    sh[t] = (t < NBLK1) ? blk_sum[t] : 0;
    __syncthreads();
    for (int off = 1; off < 256; off <<= 1) {
        int v = (t >= off) ? sh[t - off] : 0;
        __syncthreads();
        sh[t] += v;
        __syncthreads();
    }
    if (t < NBLK1) blk_off[t] = (t == 0) ? 0 : sh[t - 1];
    if (t == 0) row_ptr[N_TOTAL] = NNZ;
}

__global__ __launch_bounds__(256) void scan_phase3(const int* __restrict__ cnt,
                                                   const int* __restrict__ blk_off,
                                                   int* __restrict__ row_ptr,
                                                   int* __restrict__ cursor) {
    __shared__ int sh[256];
    int b = blockIdx.x, t = threadIdx.x;
    int base = b * SCAN_CHUNK + t * 4;
    int c[4];
    int s = 0;
#pragma unroll
    for (int i = 0; i < 4; ++i) {
        int idx = base + i;
        c[i] = (idx < N_TOTAL) ? cnt[idx] : 0;
        s += c[i];
    }
    sh[t] = s;
    __syncthreads();
    for (int off = 1; off < 256; off <<= 1) {
        int v = (t >= off) ? sh[t - off] : 0;
        __syncthreads();
        sh[t] += v;
        __syncthreads();
    }
    int run = blk_off[b] + ((t == 0) ? 0 : sh[t - 1]);
#pragma unroll
    for (int i = 0; i < 4; ++i) {
        int idx = base + i;
        if (idx < N_TOTAL) {
            row_ptr[idx] = run;
            cursor[idx] = run;
            run += c[i];
        }
    }
}

// ---------------------------------------------------------------------------
// CSR build step 3: scatter (col, val) into row-sorted order
// ---------------------------------------------------------------------------
__global__ __launch_bounds__(256) void scatter_edges(
    const int* __restrict__ rows, const int* __restrict__ cols,
    const float* __restrict__ vals, int* __restrict__ cursor,
    int* __restrict__ scol, float* __restrict__ sval) {
    int e = blockIdx.x * 256 + threadIdx.x;
    if (e >= NNZ) return;
    int r = rows[e];
    int p = atomicAdd(&cursor[r], 1);
    scol[p] = cols[e];
    sval[p] = vals[e];
}

// ---------------------------------------------------------------------------
// SpMM gather: one wave per output row, lane = dim element.
// mode bits: 1 = write y; 2 = acc += res (node rows); 4 = acc = x + res (node rows)
// ---------------------------------------------------------------------------
__global__ __launch_bounds__(256) void spmm_gather(
    const int* __restrict__ row_ptr, const int* __restrict__ scol,
    const float* __restrict__ sval, const float* __restrict__ x,
    float* __restrict__ y, float* __restrict__ acc, int nrows, int mode) {
    int wid = (blockIdx.x * 256 + threadIdx.x) >> 6;
    int lane = threadIdx.x & 63;
    if (wid >= nrows) return;
    int beg = row_ptr[wid], end = row_ptr[wid + 1];
    float res = 0.f;
    int k = beg;
    for (; k + 1 < end; k += 2) {
        int c0 = scol[k], c1 = scol[k + 1];
        float v0 = sval[k], v1 = sval[k + 1];
        res += v0 * x[(size_t)c0 * DIM + lane];
        res += v1 * x[(size_t)c1 * DIM + lane];
    }
    if (k < end) res += sval[k] * x[(size_t)scol[k] * DIM + lane];
    size_t o = (size_t)wid * DIM + lane;
    if (mode & 1) y[o] = res;
    if (wid < N_NODES) {
        if (mode & 4) acc[o] = x[o] + res;
        else if (mode & 2) acc[o] += res;
    }
}

// ---------------------------------------------------------------------------
// GEMM: Z[row, :] (+)= X[row, 0:64] @ W (64x50)
// ---------------------------------------------------------------------------
__global__ __launch_bounds__(256) void gemm_nodes(
    const float* __restrict__ X, const float* __restrict__ W,
    float* __restrict__ Z, int accumulate) {
    __shared__ float Ws[DIM * NCLASS];
    for (int i = threadIdx.x; i < DIM * NCLASS; i += 256) Ws[i] = W[i];
    __syncthreads();
    int row = blockIdx.x * blockDim.x + threadIdx.x;
    if (row >= N_NODES) return;
    float xr[DIM];
    const float4* xp = reinterpret_cast<const float4*>(X + (size_t)row * DIM);
#pragma unroll
    for (int i = 0; i < DIM / 4; ++i) reinterpret_cast<float4*>(xr)[i] = xp[i];
    float* zp = Z + (size_t)row * NCLASS;
    for (int c = 0; c < NCLASS; ++c) {
        float acc = 0.f;
#pragma unroll
        for (int k = 0; k < DIM; ++k) acc += xr[k] * Ws[k * NCLASS + c];
        if (accumulate) zp[c] += acc; else zp[c] = acc;
    }
}

// ---------------------------------------------------------------------------
// Finalize: Z = log_softmax(Z/4 + b)
// ---------------------------------------------------------------------------
__global__ __launch_bounds__(256) void finalize_kernel(
    float* __restrict__ Z, const float* __restrict__ b) {
    __shared__ float bs[NCLASS];
    if (threadIdx.x < NCLASS) bs[threadIdx.x] = b[threadIdx.x];
    __syncthreads();
    int row = blockIdx.x * blockDim.x + threadIdx.x;
    if (row >= N_NODES) return;
    float* zp = Z + (size_t)row * NCLASS;
    float z[NCLASS];
    float m = -1e30f;
#pragma unroll
    for (int c = 0; c < NCLASS; ++c) {
        z[c] = zp[c] * 0.25f + bs[c];
        m = fmaxf(m, z[c]);
    }
    float s = 0.f;
#pragma unroll
    for (int c = 0; c < NCLASS; ++c) s += __expf(z[c] - m);
    float ls = m + __logf(s);
#pragma unroll
    for (int c = 0; c < NCLASS; ++c) zp[c] = z[c] - ls;
}

extern "C" void kernel_launch(void* const* d_in, const int* in_sizes, int n_in,
                              void* d_out, int out_size, void* d_ws, size_t ws_size,
                              hipStream_t stream) {
    const float* node_emb = (const float*)d_in[0];
    const float* hyper_emb = (const float*)d_in[1];
    const float* W = (const float*)d_in[2];
    const float* b = (const float*)d_in[3];
    const float* vals = (const float*)d_in[4];
    const int* rows = (const int*)d_in[5];
    const int* cols = (const int*)d_in[6];
    float* Z = (float*)d_out;

    const size_t BUF = (size_t)N_TOTAL * DIM * 4;   // 51.2 MB
    const size_t ACC = (size_t)N_NODES * DIM * 4;   // 38.4 MB
    const size_t EDG = (size_t)NNZ * 4;             // 12.8 MB
    const size_t CNT = (size_t)N_TOTAL * 4;

    char* w = (char*)d_ws;
    float* x = (float*)w;       w += BUF;
    float* y = (float*)w;       w += BUF;
    float* sval = (float*)w;    w += EDG;
    int* scol = (int*)w;        w += EDG;
    int* cnt = (int*)w;         w += CNT;
    int* row_ptr = (int*)w;     w += CNT + 4;
    int* cursor = (int*)w;      w += CNT;
    int* blk_sum = (int*)w;     w += 4096;
    int* blk_off = (int*)w;     w += 4096;
    float* acc = (float*)w;     w += ACC;  // only used when ws permits
    const int fused = (ws_size >= (size_t)(w - (char*)d_ws));

    // ---- CSR build ----
    hipMemsetAsync(cnt, 0, CNT, stream);
    hist_rows<<<(NNZ + 255) / 256, 256, 0, stream>>>(rows, cnt);
    scan_phase1<<<NBLK1, 256, 0, stream>>>(cnt, blk_sum);
    scan_phase2<<<1, 256, 0, stream>>>(blk_sum, blk_off, row_ptr);
    scan_phase3<<<NBLK1, 256, 0, stream>>>(cnt, blk_off, row_ptr, cursor);
    scatter_edges<<<(NNZ + 255) / 256, 256, 0, stream>>>(rows, cols, vals,
                                                         cursor, scol, sval);

    // ---- Build all_emb in x ----
    hipMemcpyAsync(x, node_emb, ACC, hipMemcpyDeviceToDevice, stream);
    hipMemcpyAsync(x + (size_t)N_NODES * DIM, hyper_emb,
                   (size_t)M_HYPER * DIM * 4, hipMemcpyDeviceToDevice, stream);

    const int gemm_blocks = (N_NODES + 255) / 256;
    const int full_blocks = (N_TOTAL * 64 + 255) / 256;
    const int node_blocks = (N_NODES * 64 + 255) / 256;

    if (fused) {
        // L1: y = A x, acc = x + y   (node rows)
        spmm_gather<<<full_blocks, 256, 0, stream>>>(row_ptr, scol, sval, x, y,
                                                     acc, N_TOTAL, 1 | 4);
        // L2: x = A y, acc += x
        spmm_gather<<<full_blocks, 256, 0, stream>>>(row_ptr, scol, sval, y, x,
                                                     acc, N_TOTAL, 1 | 2);
        // L3: acc += A x (node rows only, no y write)
        spmm_gather<<<node_blocks, 256, 0, stream>>>(row_ptr, scol, sval, x, y,
                                                     acc, N_NODES, 2);
        gemm_nodes<<<gemm_blocks, 256, 0, stream>>>(acc, W, Z, 0);
    } else {
        hipMemsetAsync(Z, 0, (size_t)out_size * 4, stream);
        gemm_nodes<<<gemm_blocks, 256, 0, stream>>>(x, W, Z, 1);
        spmm_gather<<<full_blocks, 256, 0, stream>>>(row_ptr, scol, sval, x, y,
                                                     nullptr, N_TOTAL, 1);
        gemm_nodes<<<gemm_blocks, 256, 0, stream>>>(y, W, Z, 1);
        spmm_gather<<<full_blocks, 256, 0, stream>>>(row_ptr, scol, sval, y, x,
                                                     nullptr, N_TOTAL, 1);
        gemm_nodes<<<gemm_blocks, 256, 0, stream>>>(x, W, Z, 1);
        spmm_gather<<<node_blocks, 256, 0, stream>>>(row_ptr, scol, sval, x, y,
                                                     nullptr, N_NODES, 1);
        gemm_nodes<<<gemm_blocks, 256, 0, stream>>>(y, W, Z, 1);
    }
    finalize_kernel<<<gemm_blocks, 256, 0, stream>>>(Z, b);
}

// Round 4
// 982.157 us; speedup vs baseline: 8.5312x; 1.0077x over previous
//
#include <hip/hip_runtime.h>
#include <hip/hip_bf16.h>

#define N_NODES 150000
#define M_HYPER 50000
#define N_TOTAL 200000
#define DIM 64
#define NCLASS 50
#define NNZ 3200000

#define SCAN_CHUNK 1024
#define NBLK1 ((N_TOTAL + SCAN_CHUNK - 1) / SCAN_CHUNK)  // 196

// ---------------------------------------------------------------------------
// CSR build step 1: histogram of rows
// ---------------------------------------------------------------------------
__global__ __launch_bounds__(256) void hist_rows(const int* __restrict__ rows,
                                                 int* __restrict__ cnt) {
    int e = blockIdx.x * 256 + threadIdx.x;
    if (e < NNZ) atomicAdd(&cnt[rows[e]], 1);
}

// ---------------------------------------------------------------------------
// Parallel exclusive scan over cnt[N_TOTAL], 3 phases.
// ---------------------------------------------------------------------------
__global__ __launch_bounds__(256) void scan_phase1(const int* __restrict__ cnt,
                                                   int* __restrict__ blk_sum) {
    __shared__ int sh[256];
    int b = blockIdx.x, t = threadIdx.x;
    int base = b * SCAN_CHUNK + t * 4;
    int s = 0;
#pragma unroll
    for (int i = 0; i < 4; ++i) {
        int idx = base + i;
        if (idx < N_TOTAL) s += cnt[idx];
    }
    sh[t] = s;
    __syncthreads();
    for (int off = 128; off > 0; off >>= 1) {
        if (t < off) sh[t] += sh[t + off];
        __syncthreads();
    }
    if (t == 0) blk_sum[b] = sh[0];
}

__global__ __launch_bounds__(256) void scan_phase2(const int* __restrict__ blk_sum,
                                                   int* __restrict__ blk_off,
                                                   int* __restrict__ row_ptr) {
    __shared__ int sh[256];
    int t = threadIdx.x;
    sh[t] = (t < NBLK1) ? blk_sum[t] : 0;
    __syncthreads();
    for (int off = 1; off < 256; off <<= 1) {
        int v = (t >= off) ? sh[t - off] : 0;
        __syncthreads();
        sh[t] += v;
        __syncthreads();
    }
    if (t < NBLK1) blk_off[t] = (t == 0) ? 0 : sh[t - 1];
    if (t == 0) row_ptr[N_TOTAL] = NNZ;
}

__global__ __launch_bounds__(256) void scan_phase3(const int* __restrict__ cnt,
                                                   const int* __restrict__ blk_off,
                                                   int* __restrict__ row_ptr,
                                                   int* __restrict__ cursor) {
    __shared__ int sh[256];
    int b = blockIdx.x, t = threadIdx.x;
    int base = b * SCAN_CHUNK + t * 4;
    int c[4];
    int s = 0;
#pragma unroll
    for (int i = 0; i < 4; ++i) {
        int idx = base + i;
        c[i] = (idx < N_TOTAL) ? cnt[idx] : 0;
        s += c[i];
    }
    sh[t] = s;
    __syncthreads();
    for (int off = 1; off < 256; off <<= 1) {
        int v = (t >= off) ? sh[t - off] : 0;
        __syncthreads();
        sh[t] += v;
        __syncthreads();
    }
    int run = blk_off[b] + ((t == 0) ? 0 : sh[t - 1]);
#pragma unroll
    for (int i = 0; i < 4; ++i) {
        int idx = base + i;
        if (idx < N_TOTAL) {
            row_ptr[idx] = run;
            cursor[idx] = run;
            run += c[i];
        }
    }
}

// ---------------------------------------------------------------------------
// CSR build step 3: scatter packed (col, val) 8B records into row-sorted order
// ---------------------------------------------------------------------------
__global__ __launch_bounds__(256) void scatter_edges(
    const int* __restrict__ rows, const int* __restrict__ cols,
    const float* __restrict__ vals, int* __restrict__ cursor,
    int2* __restrict__ edges) {
    int e = blockIdx.x * 256 + threadIdx.x;
    if (e >= NNZ) return;
    int r = rows[e];
    int p = atomicAdd(&cursor[r], 1);
    edges[p] = make_int2(cols[e], __float_as_int(vals[e]));
}

// ---------------------------------------------------------------------------
// Build bf16 all_emb from f32 node_emb / hyper_emb. 4 elems per thread.
// ---------------------------------------------------------------------------
__global__ __launch_bounds__(256) void build_x_bf16(
    const float* __restrict__ node_emb, const float* __restrict__ hyper_emb,
    __hip_bfloat162* __restrict__ xb) {
    int i = blockIdx.x * 256 + threadIdx.x;
    size_t base = (size_t)i * 4;
    const size_t NN = (size_t)N_NODES * DIM;
    if (base >= (size_t)N_TOTAL * DIM) return;
    float4 f;
    if (base < NN)
        f = *reinterpret_cast<const float4*>(node_emb + base);
    else
        f = *reinterpret_cast<const float4*>(hyper_emb + (base - NN));
    xb[2 * i] = __float22bfloat162_rn(make_float2(f.x, f.y));
    xb[2 * i + 1] = __float22bfloat162_rn(make_float2(f.z, f.w));
}

// ---------------------------------------------------------------------------
// SpMM gather (bf16 x/y, f32 accumulate): one wave per row, lane = dim elem.
// mode bits: 1 = write y; 2 = acc += res (node rows);
//            4 = acc = node_emb_f32 + res (node rows)
// ---------------------------------------------------------------------------
__global__ __launch_bounds__(256) void spmm_gather(
    const int* __restrict__ row_ptr, const int2* __restrict__ edges,
    const __hip_bfloat16* __restrict__ x, __hip_bfloat16* __restrict__ y,
    const float* __restrict__ node_emb, float* __restrict__ acc,
    int nrows, int mode) {
    int wid = (blockIdx.x * 256 + threadIdx.x) >> 6;
    int lane = threadIdx.x & 63;
    if (wid >= nrows) return;
    int beg = row_ptr[wid], end = row_ptr[wid + 1];
    float res = 0.f;
    int k = beg;
    for (; k + 1 < end; k += 2) {
        int2 e0 = edges[k], e1 = edges[k + 1];
        float x0 = __bfloat162float(x[(size_t)e0.x * DIM + lane]);
        float x1 = __bfloat162float(x[(size_t)e1.x * DIM + lane]);
        res += __int_as_float(e0.y) * x0;
        res += __int_as_float(e1.y) * x1;
    }
    if (k < end) {
        int2 e0 = edges[k];
        res += __int_as_float(e0.y) *
               __bfloat162float(x[(size_t)e0.x * DIM + lane]);
    }
    size_t o = (size_t)wid * DIM + lane;
    if (mode & 1) y[o] = __float2bfloat16(res);
    if (wid < N_NODES) {
        if (mode & 4) acc[o] = node_emb[o] + res;
        else if (mode & 2) acc[o] += res;
    }
}

// ---------------------------------------------------------------------------
// GEMM: Z[row, :] = acc[row, 0:64] @ W (64x50)
// ---------------------------------------------------------------------------
__global__ __launch_bounds__(256) void gemm_nodes(
    const float* __restrict__ X, const float* __restrict__ W,
    float* __restrict__ Z) {
    __shared__ float Ws[DIM * NCLASS];
    for (int i = threadIdx.x; i < DIM * NCLASS; i += 256) Ws[i] = W[i];
    __syncthreads();
    int row = blockIdx.x * blockDim.x + threadIdx.x;
    if (row >= N_NODES) return;
    float xr[DIM];
    const float4* xp = reinterpret_cast<const float4*>(X + (size_t)row * DIM);
#pragma unroll
    for (int i = 0; i < DIM / 4; ++i) reinterpret_cast<float4*>(xr)[i] = xp[i];
    float* zp = Z + (size_t)row * NCLASS;
    for (int c = 0; c < NCLASS; ++c) {
        float acc = 0.f;
#pragma unroll
        for (int k = 0; k < DIM; ++k) acc += xr[k] * Ws[k * NCLASS + c];
        zp[c] = acc;
    }
}

// ---------------------------------------------------------------------------
// Finalize: Z = log_softmax(Z/4 + b)
// ---------------------------------------------------------------------------
__global__ __launch_bounds__(256) void finalize_kernel(
    float* __restrict__ Z, const float* __restrict__ b) {
    __shared__ float bs[NCLASS];
    if (threadIdx.x < NCLASS) bs[threadIdx.x] = b[threadIdx.x];
    __syncthreads();
    int row = blockIdx.x * blockDim.x + threadIdx.x;
    if (row >= N_NODES) return;
    float* zp = Z + (size_t)row * NCLASS;
    float z[NCLASS];
    float m = -1e30f;
#pragma unroll
    for (int c = 0; c < NCLASS; ++c) {
        z[c] = zp[c] * 0.25f + bs[c];
        m = fmaxf(m, z[c]);
    }
    float s = 0.f;
#pragma unroll
    for (int c = 0; c < NCLASS; ++c) s += __expf(z[c] - m);
    float ls = m + __logf(s);
#pragma unroll
    for (int c = 0; c < NCLASS; ++c) zp[c] = z[c] - ls;
}

extern "C" void kernel_launch(void* const* d_in, const int* in_sizes, int n_in,
                              void* d_out, int out_size, void* d_ws, size_t ws_size,
                              hipStream_t stream) {
    const float* node_emb = (const float*)d_in[0];
    const float* hyper_emb = (const float*)d_in[1];
    const float* W = (const float*)d_in[2];
    const float* b = (const float*)d_in[3];
    const float* vals = (const float*)d_in[4];
    const int* rows = (const int*)d_in[5];
    const int* cols = (const int*)d_in[6];
    float* Z = (float*)d_out;

    const size_t BUFB = (size_t)N_TOTAL * DIM * 2;  // 25.6 MB (bf16)
    const size_t ACC = (size_t)N_NODES * DIM * 4;   // 38.4 MB (f32)
    const size_t EDG = (size_t)NNZ * 8;             // 25.6 MB (int2)
    const size_t CNT = (size_t)N_TOTAL * 4;

    char* w = (char*)d_ws;
    __hip_bfloat16* xb = (__hip_bfloat16*)w;  w += BUFB;
    __hip_bfloat16* yb = (__hip_bfloat16*)w;  w += BUFB;
    int2* edges = (int2*)w;                   w += EDG;
    float* acc = (float*)w;                   w += ACC;
    int* cnt = (int*)w;                       w += CNT;
    int* row_ptr = (int*)w;                   w += CNT + 8;
    int* cursor = (int*)w;                    w += CNT;
    int* blk_sum = (int*)w;                   w += 4096;
    int* blk_off = (int*)w;

    // ---- CSR build ----
    hipMemsetAsync(cnt, 0, CNT, stream);
    hist_rows<<<(NNZ + 255) / 256, 256, 0, stream>>>(rows, cnt);
    scan_phase1<<<NBLK1, 256, 0, stream>>>(cnt, blk_sum);
    scan_phase2<<<1, 256, 0, stream>>>(blk_sum, blk_off, row_ptr);
    scan_phase3<<<NBLK1, 256, 0, stream>>>(cnt, blk_off, row_ptr, cursor);
    scatter_edges<<<(NNZ + 255) / 256, 256, 0, stream>>>(rows, cols, vals,
                                                         cursor, edges);

    // ---- Build bf16 all_emb ----
    const int cvt_blocks = (int)(((size_t)N_TOTAL * DIM / 4 + 255) / 256);
    build_x_bf16<<<cvt_blocks, 256, 0, stream>>>(node_emb, hyper_emb,
                                                 (__hip_bfloat162*)xb);

    const int gemm_blocks = (N_NODES + 255) / 256;
    const int full_blocks = (N_TOTAL * 64 + 255) / 256;
    const int node_blocks = (N_NODES * 64 + 255) / 256;

    // L1: y = A x, acc = node_emb + y (node rows)
    spmm_gather<<<full_blocks, 256, 0, stream>>>(row_ptr, edges, xb, yb,
                                                 node_emb, acc, N_TOTAL, 1 | 4);
    // L2: x = A y, acc += x
    spmm_gather<<<full_blocks, 256, 0, stream>>>(row_ptr, edges, yb, xb,
                                                 nullptr, acc, N_TOTAL, 1 | 2);
    // L3: acc += A x (node rows only, no y write)
    spmm_gather<<<node_blocks, 256, 0, stream>>>(row_ptr, edges, xb, yb,
                                                 nullptr, acc, N_NODES, 2);
    gemm_nodes<<<gemm_blocks, 256, 0, stream>>>(acc, W, Z);
    finalize_kernel<<<gemm_blocks, 256, 0, stream>>>(Z, b);
}